// Round 1
// baseline (2338.613 us; speedup 1.0000x reference)
//
#include <hip/hip_runtime.h>

// ---------------- problem constants ----------------
constexpr int N_NODES = 50000;
constexpr int E_TOTAL = 800000;
constexpr int IN_CH   = 16;
constexpr int OUT_CH  = 16;
constexpr int HID     = 100;

constexpr int EB  = 64;    // edges per block
constexpr int TPB = 256;   // threads per block

// ---------------- LDS layout (float offsets) ----------------
// W2s [100][104] at 0; W3s [100][104] at 10400.
// W4 half [100][128] overlays offset 0 after L3 (12800 <= 20800).
constexpr int OFF_W2   = 0;
constexpr int OFF_W3   = 10400;
constexpr int OFF_W4   = 0;
constexpr int OFF_HA   = 20800;   // hT [100][68]
constexpr int OFF_HB   = 27600;   // hT [100][68]
constexpr int OFF_W1   = 34400;   // [8][104]
constexpr int OFF_B1   = 35232;   // [104]
constexpr int OFF_B2   = 35336;   // [104]
constexpr int OFF_B3   = 35440;   // [104]
constexpr int OFF_B4   = 35544;   // [256]
constexpr int OFF_EAT  = 35800;   // eaT [8][68]
constexpr int OFF_XS   = 36344;   // x_src [64][20]
constexpr int OFF_DST  = 37624;   // [64] ints
constexpr int SMEM_FLOATS = 37688;
constexpr int SMEM_BYTES  = SMEM_FLOATS * 4;   // 150752 B < 160 KiB

// One MLP layer on a 64-edge tile:
//   out[e][col] = act( bias[col] + sum_k in[e][k] * W[k][col] )
// in/out stored transposed in LDS: hT[k][e], row stride = given.
// Thread (c = t&31, g = t>>5) computes cols 4c..4c+3 for edges 8g..8g+7.
template<int K, bool RELU>
__device__ inline void mlp_layer(float* sm, int c, int g,
                                 int inOff, int inStride,
                                 int wOff, int wStride,
                                 int bOff, int outOff)
{
    float acc[8][4];
#pragma unroll
    for (int j = 0; j < 4; ++j) {
        const float bb = sm[bOff + 4 * c + j];
#pragma unroll
        for (int e = 0; e < 8; ++e) acc[e][j] = bb;
    }
#pragma unroll 4
    for (int k = 0; k < K; ++k) {
        const float4 h0 = *reinterpret_cast<const float4*>(&sm[inOff + k * inStride + 8 * g]);
        const float4 h1 = *reinterpret_cast<const float4*>(&sm[inOff + k * inStride + 8 * g + 4]);
        const float4 w4 = *reinterpret_cast<const float4*>(&sm[wOff + k * wStride + 4 * c]);
        const float hh[8] = {h0.x, h0.y, h0.z, h0.w, h1.x, h1.y, h1.z, h1.w};
        const float ww[4] = {w4.x, w4.y, w4.z, w4.w};
#pragma unroll
        for (int e = 0; e < 8; ++e)
#pragma unroll
            for (int j = 0; j < 4; ++j)
                acc[e][j] = fmaf(hh[e], ww[j], acc[e][j]);
    }
    // store transposed with optional relu; pad cols (>=100) are discarded
#pragma unroll
    for (int j = 0; j < 4; ++j) {
        const int col = 4 * c + j;
        if (col < HID) {
            float v[8];
#pragma unroll
            for (int e = 0; e < 8; ++e)
                v[e] = RELU ? fmaxf(acc[e][j], 0.f) : acc[e][j];
            *reinterpret_cast<float4*>(&sm[outOff + col * 68 + 8 * g])     = make_float4(v[0], v[1], v[2], v[3]);
            *reinterpret_cast<float4*>(&sm[outOff + col * 68 + 8 * g + 4]) = make_float4(v[4], v[5], v[6], v[7]);
        }
    }
}

__global__ __launch_bounds__(TPB, 1)
void edge_kernel(const float* __restrict__ x, const int* __restrict__ eidx,
                 const float* __restrict__ ea,
                 const float* __restrict__ W1, const float* __restrict__ b1,
                 const float* __restrict__ W2, const float* __restrict__ b2,
                 const float* __restrict__ W3, const float* __restrict__ b3,
                 const float* __restrict__ W4, const float* __restrict__ b4,
                 float* __restrict__ out, float* __restrict__ cnt)
{
    extern __shared__ float sm[];
    const int t  = threadIdx.x;
    const int e0 = blockIdx.x * EB;
    const int c  = t & 31;
    const int g  = t >> 5;

    // ---------------- stage weights & per-edge data ----------------
    for (int idx = t; idx < 100 * 104; idx += TPB) {
        const int r = idx / 104, cc = idx - r * 104;
        const bool ok = cc < HID;
        sm[OFF_W2 + idx] = ok ? W2[r * HID + cc] : 0.f;
        sm[OFF_W3 + idx] = ok ? W3[r * HID + cc] : 0.f;
    }
    for (int idx = t; idx < 8 * 104; idx += TPB) {
        const int r = idx / 104, cc = idx - r * 104;
        sm[OFF_W1 + idx] = (cc < HID) ? W1[r * HID + cc] : 0.f;
    }
    if (t < 104) {
        const bool ok = t < HID;
        sm[OFF_B1 + t] = ok ? b1[t] : 0.f;
        sm[OFF_B2 + t] = ok ? b2[t] : 0.f;
        sm[OFF_B3 + t] = ok ? b3[t] : 0.f;
    }
    sm[OFF_B4 + t] = b4[t];   // t in [0,256)

    int* dsti = reinterpret_cast<int*>(sm + OFF_DST);
    if (t < EB) {
        const int d = eidx[E_TOTAL + e0 + t];
        dsti[t] = d;
        unsafeAtomicAdd(&cnt[d], 1.0f);
    }
    if (t < 128) {  // edge_attr, transposed: eaT[k][e]
        const int e = t >> 1, hh = t & 1;
        const float4 v = *reinterpret_cast<const float4*>(&ea[(size_t)(e0 + e) * 8 + hh * 4]);
        sm[OFF_EAT + (hh * 4 + 0) * 68 + e] = v.x;
        sm[OFF_EAT + (hh * 4 + 1) * 68 + e] = v.y;
        sm[OFF_EAT + (hh * 4 + 2) * 68 + e] = v.z;
        sm[OFF_EAT + (hh * 4 + 3) * 68 + e] = v.w;
    }
    {   // gather x[src[e]] -> xs[64][20]
        const int e = t >> 2, q = t & 3;
        const int s = eidx[e0 + e];
        const float4 v = *reinterpret_cast<const float4*>(&x[(size_t)s * IN_CH + q * 4]);
        *reinterpret_cast<float4*>(&sm[OFF_XS + e * 20 + q * 4]) = v;
    }
    __syncthreads();

    // ---------------- edge MLP ----------------
    mlp_layer<8,   true>(sm, c, g, OFF_EAT, 68, OFF_W1, 104, OFF_B1, OFF_HA);
    __syncthreads();
    mlp_layer<HID, true>(sm, c, g, OFF_HA,  68, OFF_W2, 104, OFF_B2, OFF_HB);
    __syncthreads();
    mlp_layer<HID, true>(sm, c, g, OFF_HB,  68, OFF_W3, 104, OFF_B3, OFF_HA);
    __syncthreads();

    // ---------------- L4 (w = h3 @ W4 + b4) in two 128-col halves + message ----------------
    float part[8][4];
#pragma unroll
    for (int e = 0; e < 8; ++e)
#pragma unroll
        for (int j = 0; j < 4; ++j) part[e][j] = 0.f;

    for (int h = 0; h < 2; ++h) {
        // stage W4 half into the (now free) W2/W3 region
        for (int idx = t; idx < 100 * 128; idx += TPB) {
            const int r = idx >> 7, cc = idx & 127;
            sm[OFF_W4 + idx] = W4[r * 256 + 128 * h + cc];
        }
        __syncthreads();

        float acc[8][4];
#pragma unroll
        for (int j = 0; j < 4; ++j) {
            const float bb = sm[OFF_B4 + 128 * h + 4 * c + j];
#pragma unroll
            for (int e = 0; e < 8; ++e) acc[e][j] = bb;
        }
#pragma unroll 4
        for (int k = 0; k < HID; ++k) {
            const float4 h0 = *reinterpret_cast<const float4*>(&sm[OFF_HA + k * 68 + 8 * g]);
            const float4 h1 = *reinterpret_cast<const float4*>(&sm[OFF_HA + k * 68 + 8 * g + 4]);
            const float4 w4 = *reinterpret_cast<const float4*>(&sm[OFF_W4 + k * 128 + 4 * c]);
            const float hh[8] = {h0.x, h0.y, h0.z, h0.w, h1.x, h1.y, h1.z, h1.w};
            const float ww[4] = {w4.x, w4.y, w4.z, w4.w};
#pragma unroll
            for (int e = 0; e < 8; ++e)
#pragma unroll
                for (int j = 0; j < 4; ++j)
                    acc[e][j] = fmaf(hh[e], ww[j], acc[e][j]);
        }
        // message partial: col = i*16 + o ; this thread holds i = (c>>2) + 8h,
        // o = 4*(c&3)+j for its 8 edges
        const int i = (c >> 2) + 8 * h;
#pragma unroll
        for (int e = 0; e < 8; ++e) {
            const float xs = sm[OFF_XS + (8 * g + e) * 20 + i];
#pragma unroll
            for (int j = 0; j < 4; ++j)
                part[e][j] = fmaf(xs, acc[e][j], part[e][j]);
        }
        __syncthreads();   // before restaging W4 (h=0) / harmless (h=1)
    }

    // butterfly-reduce over the 8 i-groups (lane bits 2..4)
#pragma unroll
    for (int mask = 4; mask <= 16; mask <<= 1) {
#pragma unroll
        for (int e = 0; e < 8; ++e)
#pragma unroll
            for (int j = 0; j < 4; ++j)
                part[e][j] += __shfl_xor(part[e][j], mask, 64);
    }

    // lanes c<4 hold msg[e][4c..4c+3] -> scatter-add into out (pre-zeroed)
    if ((c & 28) == 0) {
#pragma unroll
        for (int e = 0; e < 8; ++e) {
            const int d = dsti[8 * g + e];
#pragma unroll
            for (int j = 0; j < 4; ++j)
                unsafeAtomicAdd(&out[(size_t)d * OUT_CH + 4 * c + j], part[e][j]);
        }
    }
}

// out[n][o] = x[n]@root[:,o] + out[n][o]/max(cnt[n],1) + bias[o]   (in place)
__global__ __launch_bounds__(256)
void node_kernel(const float* __restrict__ x, const float* __restrict__ root,
                 const float* __restrict__ bias, const float* __restrict__ cnt,
                 float* __restrict__ out)
{
    const int n = blockIdx.x * blockDim.x + threadIdx.x;
    if (n >= N_NODES) return;
    float xr[16];
#pragma unroll
    for (int q = 0; q < 4; ++q) {
        const float4 v = *reinterpret_cast<const float4*>(&x[(size_t)n * IN_CH + 4 * q]);
        xr[4 * q] = v.x; xr[4 * q + 1] = v.y; xr[4 * q + 2] = v.z; xr[4 * q + 3] = v.w;
    }
    const float inv = 1.f / fmaxf(cnt[n], 1.f);
#pragma unroll
    for (int q = 0; q < 4; ++q) {
        float4 o4 = *reinterpret_cast<float4*>(&out[(size_t)n * OUT_CH + 4 * q]);
        float res[4];
#pragma unroll
        for (int j = 0; j < 4; ++j) {
            const int o = 4 * q + j;
            float dot = 0.f;
#pragma unroll
            for (int i = 0; i < 16; ++i)
                dot = fmaf(xr[i], root[i * OUT_CH + o], dot);
            res[j] = dot + (&o4.x)[j] * inv + bias[o];
        }
        *reinterpret_cast<float4*>(&out[(size_t)n * OUT_CH + 4 * q]) = make_float4(res[0], res[1], res[2], res[3]);
    }
}

extern "C" void kernel_launch(void* const* d_in, const int* in_sizes, int n_in,
                              void* d_out, int out_size, void* d_ws, size_t ws_size,
                              hipStream_t stream)
{
    const float* x    = (const float*)d_in[0];
    const int*   eidx = (const int*)  d_in[1];
    const float* ea   = (const float*)d_in[2];
    const float* W1   = (const float*)d_in[3];
    const float* b1   = (const float*)d_in[4];
    const float* W2   = (const float*)d_in[5];
    const float* b2   = (const float*)d_in[6];
    const float* W3   = (const float*)d_in[7];
    const float* b3   = (const float*)d_in[8];
    const float* W4   = (const float*)d_in[9];
    const float* b4   = (const float*)d_in[10];
    const float* root = (const float*)d_in[11];
    const float* bias = (const float*)d_in[12];
    float* out = (float*)d_out;
    float* cnt = (float*)d_ws;   // N_NODES floats

    (void)in_sizes; (void)n_in; (void)ws_size;

    // allow >64KB dynamic LDS (idempotent; same work every call)
    hipFuncSetAttribute((const void*)edge_kernel,
                        hipFuncAttributeMaxDynamicSharedMemorySize, SMEM_BYTES);

    hipMemsetAsync(d_out, 0, (size_t)out_size * sizeof(float), stream);
    hipMemsetAsync(d_ws, 0, (size_t)N_NODES * sizeof(float), stream);

    hipLaunchKernelGGL(edge_kernel, dim3(E_TOTAL / EB), dim3(TPB), SMEM_BYTES, stream,
                       x, eidx, ea, W1, b1, W2, b2, W3, b3, W4, b4, out, cnt);
    hipLaunchKernelGGL(node_kernel, dim3((N_NODES + 255) / 256), dim3(256), 0, stream,
                       x, root, bias, cnt, out);
}

// Round 2
// 428.389 us; speedup vs baseline: 5.4591x; 5.4591x over previous
//
#include <hip/hip_runtime.h>
#include <hip/hip_bf16.h>

// ---------------- problem constants ----------------
constexpr int N_NODES = 50000;
constexpr int E_TOTAL = 800000;
constexpr int EB  = 128;   // edges per block
constexpr int TPB = 512;   // 8 waves

typedef __attribute__((ext_vector_type(8))) short bf16x8;
typedef __attribute__((ext_vector_type(4))) float f32x4;

// ---------------- workspace byte offsets ----------------
constexpr size_t WS_CNT = 0;                    // N_NODES f32
constexpr size_t WS_W1  = 200704;               // [128][128] bf16, pre-swizzled
constexpr size_t WS_W2  = WS_W1 + 32768;        // [128][128]
constexpr size_t WS_W3  = WS_W2 + 32768;        // [128][128]
constexpr size_t WS_W4  = WS_W3 + 32768;        // [256][128] (two 32KB halves)

// ---------------- LDS byte offsets ----------------
constexpr int L_X   = 0;        // [128][128] bf16 (ping)  / msg_buf f32 [128][16] at end
constexpr int L_Y   = 32768;    // [128][128] bf16 (pong)
constexpr int L_WA  = 65536;    // weight buffer A
constexpr int L_WB  = 98304;    // weight buffer B
constexpr int L_XS  = 131072;   // x_src [128][16] f32
constexpr int L_B1  = 139264;   // 128 f32
constexpr int L_B2  = L_B1 + 512;
constexpr int L_B3  = L_B2 + 512;
constexpr int L_B4  = L_B3 + 512;   // 256 f32
constexpr int L_DST = L_B4 + 1024;  // 128 i32
constexpr int L_TOT = L_DST + 512;  // 142336 B

__device__ inline unsigned short bfb(float f) {
    __hip_bfloat16 h = __float2bfloat16(f);
    return __builtin_bit_cast(unsigned short, h);
}
__device__ inline unsigned pk2(float a, float b) {
    return (unsigned)bfb(a) | ((unsigned)bfb(b) << 16);
}

// async 16B/lane global->LDS copy; bytes must be a multiple of 1024
__device__ inline void stage(const char* g, char* l, int bytes, int t) {
    const int wave = t >> 6, lane = t & 63;
    for (int c = wave; c * 1024 < bytes; c += 8) {
        __builtin_amdgcn_global_load_lds(
            (const __attribute__((address_space(1))) void*)(g + c * 1024 + lane * 16),
            (__attribute__((address_space(3))) void*)(l + c * 1024), 16, 0, 0);
    }
}

// One padded-128 MFMA layer: out[e][n] = relu(bias[n] + sum_k in[e][k]*W[n][k])
// LDS tiles [128 rows][128 bf16], row stride 256B, byte ^ ((row&7)<<4) swizzle.
template<int KSTEPS, bool RELU>
__device__ inline void layer(char* sm, int inOff, int outOff, int wOff, int bOff,
                             int wm, int wn, int lane)
{
    const int r16 = lane & 15, g4 = lane >> 4;
    const int R0 = 32 * wm, C0 = 64 * wn;
    f32x4 acc[2][4] = {};
#pragma unroll
    for (int ks = 0; ks < KSTEPS; ++ks) {
        const int kb = ks * 64 + g4 * 16;   // this lane's 16B slot within the row
        bf16x8 a[2], b[4];
#pragma unroll
        for (int mb = 0; mb < 2; ++mb) {
            const int r = R0 + 16 * mb + r16;
            a[mb] = *reinterpret_cast<const bf16x8*>(sm + inOff + r * 256 + (kb ^ ((r & 7) << 4)));
        }
#pragma unroll
        for (int nf = 0; nf < 4; ++nf) {
            const int n = C0 + 16 * nf + r16;
            b[nf] = *reinterpret_cast<const bf16x8*>(sm + wOff + n * 256 + (kb ^ ((n & 7) << 4)));
        }
#pragma unroll
        for (int mb = 0; mb < 2; ++mb)
#pragma unroll
            for (int nf = 0; nf < 4; ++nf)
                acc[mb][nf] = __builtin_amdgcn_mfma_f32_16x16x32_bf16(a[mb], b[nf], acc[mb][nf], 0, 0, 0);
    }
    const float* bl = reinterpret_cast<const float*>(sm + bOff);
#pragma unroll
    for (int nf = 0; nf < 4; ++nf) {
        const int n = C0 + 16 * nf + r16;
        const float bb = bl[n];
#pragma unroll
        for (int mb = 0; mb < 2; ++mb)
#pragma unroll
            for (int j = 0; j < 4; ++j) {
                const int r = R0 + 16 * mb + g4 * 4 + j;
                float v = acc[mb][nf][j] + bb;
                if (RELU) v = fmaxf(v, 0.f);
                *reinterpret_cast<unsigned short*>(sm + outOff + r * 256 + ((2 * n) ^ ((r & 7) << 4))) = bfb(v);
            }
    }
}

// L4 half: w[e][n] = acc + b4[n]; fold msg[e][o] += x_src[e][i]*w, i=n>>4, o=n&15
__device__ inline void layer4_half(char* sm, int inOff, int wOff, int h,
                                   int wm, int wn, int lane, float mp[2][4])
{
    const int r16 = lane & 15, g4 = lane >> 4;
    const int R0 = 32 * wm, C0 = 64 * wn;
    f32x4 acc[2][4] = {};
#pragma unroll
    for (int ks = 0; ks < 4; ++ks) {
        const int kb = ks * 64 + g4 * 16;
        bf16x8 a[2], b[4];
#pragma unroll
        for (int mb = 0; mb < 2; ++mb) {
            const int r = R0 + 16 * mb + r16;
            a[mb] = *reinterpret_cast<const bf16x8*>(sm + inOff + r * 256 + (kb ^ ((r & 7) << 4)));
        }
#pragma unroll
        for (int nf = 0; nf < 4; ++nf) {
            const int n = C0 + 16 * nf + r16;
            b[nf] = *reinterpret_cast<const bf16x8*>(sm + wOff + n * 256 + (kb ^ ((n & 7) << 4)));
        }
#pragma unroll
        for (int mb = 0; mb < 2; ++mb)
#pragma unroll
            for (int nf = 0; nf < 4; ++nf)
                acc[mb][nf] = __builtin_amdgcn_mfma_f32_16x16x32_bf16(a[mb], b[nf], acc[mb][nf], 0, 0, 0);
    }
    const float* b4l = reinterpret_cast<const float*>(sm + L_B4);
    const float* xs  = reinterpret_cast<const float*>(sm + L_XS);
#pragma unroll
    for (int nf = 0; nf < 4; ++nf) {
        const int n16 = C0 + 16 * nf;
        const int i   = 8 * h + 4 * wn + nf;      // input channel for this fragment
        const float bb = b4l[128 * h + n16 + r16];
#pragma unroll
        for (int mb = 0; mb < 2; ++mb)
#pragma unroll
            for (int j = 0; j < 4; ++j) {
                const int e = R0 + 16 * mb + g4 * 4 + j;
                mp[mb][j] = fmaf(xs[e * 16 + i], acc[mb][nf][j] + bb, mp[mb][j]);
            }
    }
}

__global__ __launch_bounds__(TPB, 1)
void edge_kernel(const float* __restrict__ x, const int* __restrict__ eidx,
                 const float* __restrict__ ea,
                 const float* __restrict__ b1, const float* __restrict__ b2,
                 const float* __restrict__ b3, const float* __restrict__ b4,
                 const char* __restrict__ ws,
                 float* __restrict__ out, float* __restrict__ cnt)
{
    extern __shared__ char sm[];
    const int t    = threadIdx.x;
    const int lane = t & 63;
    const int wave = t >> 6;
    const int wm   = wave >> 1, wn = wave & 1;
    const int e0   = blockIdx.x * EB;

    // ---- issue weight prefetch for L1/L2, stage per-edge data ----
    stage(ws + WS_W1, sm + L_WA, 32768, t);
    stage(ws + WS_W2, sm + L_WB, 32768, t);

    {   // edge_attr -> bf16 into X (k 0..7), zero-fill k 8..63 (physical slots 0..7)
        const int e = t >> 2, q = t & 3;
        const int sw = (e & 7) << 4;
        if (q < 2) {
            const float4 v = *reinterpret_cast<const float4*>(&ea[(size_t)(e0 + e) * 8 + 4 * q]);
            uint2 pk; pk.x = pk2(v.x, v.y); pk.y = pk2(v.z, v.w);
            *reinterpret_cast<uint2*>(sm + L_X + e * 256 + ((8 * q) ^ sw)) = pk;
        }
        const float4 z = make_float4(0.f, 0.f, 0.f, 0.f);
        if (q == 0) {
            *reinterpret_cast<float4*>(sm + L_X + e * 256 + (64 ^ sw)) = z;
        } else {
            *reinterpret_cast<float4*>(sm + L_X + e * 256 + ((16 * q) ^ sw)) = z;
            *reinterpret_cast<float4*>(sm + L_X + e * 256 + ((16 * q + 64) ^ sw)) = z;
        }
        // gather x[src]
        const int s = eidx[e0 + e];
        const float4 xv = *reinterpret_cast<const float4*>(&x[(size_t)s * 16 + 4 * q]);
        *reinterpret_cast<float4*>(sm + L_XS + e * 64 + 16 * q) = xv;
    }
    if (t < 128) {
        float* B1 = reinterpret_cast<float*>(sm + L_B1);
        float* B2 = reinterpret_cast<float*>(sm + L_B2);
        float* B3 = reinterpret_cast<float*>(sm + L_B3);
        const bool ok = t < 100;
        B1[t] = ok ? b1[t] : 0.f;
        B2[t] = ok ? b2[t] : 0.f;
        B3[t] = ok ? b3[t] : 0.f;
        const int d = eidx[E_TOTAL + e0 + t];
        reinterpret_cast<int*>(sm + L_DST)[t] = d;
        unsafeAtomicAdd(&cnt[d], 1.0f);
    }
    if (t < 256) reinterpret_cast<float*>(sm + L_B4)[t] = b4[t];
    __syncthreads();                       // drains W1/W2 loads too

    layer<1, true>(sm, L_X, L_Y, L_WA, L_B1, wm, wn, lane);   // L1
    __syncthreads();
    stage(ws + WS_W3, sm + L_WA, 32768, t);                   // W3 in flight over L2
    layer<4, true>(sm, L_Y, L_X, L_WB, L_B2, wm, wn, lane);   // L2
    __syncthreads();
    stage(ws + WS_W4, sm + L_WB, 32768, t);                   // W4 half0 over L3
    layer<4, true>(sm, L_X, L_Y, L_WA, L_B3, wm, wn, lane);   // L3
    __syncthreads();
    stage(ws + WS_W4 + 32768, sm + L_WA, 32768, t);           // W4 half1 over L4h0

    float mp[2][4] = {};
    layer4_half(sm, L_Y, L_WB, 0, wm, wn, lane, mp);
    __syncthreads();                       // drains half1
    layer4_half(sm, L_Y, L_WA, 1, wm, wn, lane, mp);

    // ---- combine the two n-wave partials in LDS (X region is free) ----
    float* msgb = reinterpret_cast<float*>(sm + L_X);
    const int r16 = lane & 15, g4 = lane >> 4;
    if (wn == 0) {
#pragma unroll
        for (int mb = 0; mb < 2; ++mb)
#pragma unroll
            for (int j = 0; j < 4; ++j) {
                const int e = 32 * wm + 16 * mb + g4 * 4 + j;
                msgb[e * 16 + r16] = mp[mb][j];
            }
    }
    __syncthreads();
    if (wn == 1) {
#pragma unroll
        for (int mb = 0; mb < 2; ++mb)
#pragma unroll
            for (int j = 0; j < 4; ++j) {
                const int e = 32 * wm + 16 * mb + g4 * 4 + j;
                msgb[e * 16 + r16] += mp[mb][j];
            }
    }
    __syncthreads();

    // ---- scatter-add messages ----
    {
        const int e = t >> 2, o0 = 4 * (t & 3);
        const float4 mv = *reinterpret_cast<const float4*>(sm + L_X + (e * 16 + o0) * 4);
        const int d = reinterpret_cast<const int*>(sm + L_DST)[e];
        unsafeAtomicAdd(&out[(size_t)d * 16 + o0 + 0], mv.x);
        unsafeAtomicAdd(&out[(size_t)d * 16 + o0 + 1], mv.y);
        unsafeAtomicAdd(&out[(size_t)d * 16 + o0 + 2], mv.z);
        unsafeAtomicAdd(&out[(size_t)d * 16 + o0 + 3], mv.w);
    }
}

// build pre-swizzled bf16 weight images in ws: rows = output channel n, cols = k
__global__ __launch_bounds__(256)
void prep_kernel(const float* __restrict__ W1, const float* __restrict__ W2,
                 const float* __restrict__ W3, const float* __restrict__ W4,
                 char* __restrict__ ws)
{
    const int id = blockIdx.x * 256 + threadIdx.x;   // 640 rows x 128 k
    if (id >= 640 * 128) return;
    const int ng = id >> 7, k = id & 127;
    float v = 0.f;
    if (ng < 128)       { const int n = ng;       if (n < 100 && k < 8)   v = W1[k * 100 + n]; }
    else if (ng < 256)  { const int n = ng - 128; if (n < 100 && k < 100) v = W2[k * 100 + n]; }
    else if (ng < 384)  { const int n = ng - 256; if (n < 100 && k < 100) v = W3[k * 100 + n]; }
    else                { const int n = ng - 384; if (k < 100)            v = W4[k * 256 + n]; }
    *reinterpret_cast<unsigned short*>(ws + WS_W1 + ng * 256 + ((2 * k) ^ ((ng & 7) << 4))) = bfb(v);
}

// out[n][o] = x[n]@root[:,o] + out[n][o]/max(cnt[n],1) + bias[o]   (in place)
__global__ __launch_bounds__(256)
void node_kernel(const float* __restrict__ x, const float* __restrict__ root,
                 const float* __restrict__ bias, const float* __restrict__ cnt,
                 float* __restrict__ out)
{
    const int n = blockIdx.x * blockDim.x + threadIdx.x;
    if (n >= N_NODES) return;
    float xr[16];
#pragma unroll
    for (int q = 0; q < 4; ++q) {
        const float4 v = *reinterpret_cast<const float4*>(&x[(size_t)n * 16 + 4 * q]);
        xr[4 * q] = v.x; xr[4 * q + 1] = v.y; xr[4 * q + 2] = v.z; xr[4 * q + 3] = v.w;
    }
    const float inv = 1.f / fmaxf(cnt[n], 1.f);
#pragma unroll
    for (int q = 0; q < 4; ++q) {
        float4 o4 = *reinterpret_cast<float4*>(&out[(size_t)n * 16 + 4 * q]);
        float res[4];
#pragma unroll
        for (int j = 0; j < 4; ++j) {
            const int o = 4 * q + j;
            float dot = 0.f;
#pragma unroll
            for (int i = 0; i < 16; ++i)
                dot = fmaf(xr[i], root[i * 16 + o], dot);
            res[j] = dot + (&o4.x)[j] * inv + bias[o];
        }
        *reinterpret_cast<float4*>(&out[(size_t)n * 16 + 4 * q]) = make_float4(res[0], res[1], res[2], res[3]);
    }
}

extern "C" void kernel_launch(void* const* d_in, const int* in_sizes, int n_in,
                              void* d_out, int out_size, void* d_ws, size_t ws_size,
                              hipStream_t stream)
{
    const float* x    = (const float*)d_in[0];
    const int*   eidx = (const int*)  d_in[1];
    const float* ea   = (const float*)d_in[2];
    const float* W1   = (const float*)d_in[3];
    const float* b1   = (const float*)d_in[4];
    const float* W2   = (const float*)d_in[5];
    const float* b2   = (const float*)d_in[6];
    const float* W3   = (const float*)d_in[7];
    const float* b3   = (const float*)d_in[8];
    const float* W4   = (const float*)d_in[9];
    const float* b4   = (const float*)d_in[10];
    const float* root = (const float*)d_in[11];
    const float* bias = (const float*)d_in[12];
    float* out = (float*)d_out;
    char*  ws  = (char*)d_ws;
    float* cnt = (float*)d_ws;          // N_NODES f32 at offset 0

    (void)in_sizes; (void)n_in; (void)ws_size;

    hipFuncSetAttribute((const void*)edge_kernel,
                        hipFuncAttributeMaxDynamicSharedMemorySize, L_TOT);

    hipMemsetAsync(d_out, 0, (size_t)out_size * sizeof(float), stream);
    hipMemsetAsync(d_ws, 0, (size_t)N_NODES * sizeof(float), stream);

    hipLaunchKernelGGL(prep_kernel, dim3(320), dim3(256), 0, stream, W1, W2, W3, W4, ws);
    hipLaunchKernelGGL(edge_kernel, dim3(E_TOTAL / EB), dim3(TPB), L_TOT, stream,
                       x, eidx, ea, b1, b2, b3, b4, ws, out, cnt);
    hipLaunchKernelGGL(node_kernel, dim3((N_NODES + 255) / 256), dim3(256), 0, stream,
                       x, root, bias, cnt, out);
}

// Round 3
// 340.134 us; speedup vs baseline: 6.8756x; 1.2595x over previous
//
#include <hip/hip_runtime.h>
#include <hip/hip_bf16.h>

// ---------------- problem constants ----------------
constexpr int N_NODES = 50000;
constexpr int E_TOTAL = 800000;
constexpr int EB  = 64;    // edges per block
constexpr int TPB = 512;   // 8 waves: 4 m-waves x 2 n-waves

typedef __attribute__((ext_vector_type(8))) short bf16x8;
typedef __attribute__((ext_vector_type(4))) float f32x4;
typedef __attribute__((ext_vector_type(4))) unsigned int u32x4;

// ---------------- workspace byte offsets (linear bf16 images) ----------------
constexpr size_t WS_CNT = 0;                  // N_NODES f32
constexpr size_t WS_W1  = 200704;             // [128 n][32 k]  = 8192 B
constexpr size_t WS_W2  = WS_W1 + 8192;       // [128 n][128 k] = 32768 B
constexpr size_t WS_W3  = WS_W2 + 32768;      // [128 n][128 k]
constexpr size_t WS_W4  = WS_W3 + 32768;      // [256 n][128 k] = 65536 B

// ---------------- LDS byte offsets (total 80640 <= 80KiB -> 2 blocks/CU) ----
constexpr int L_X   = 0;        // [64 e][256 B] bf16 ping ; later msg [64][16] f32
constexpr int L_Y   = 16384;    // [64][256 B] pong
constexpr int L_W   = 32768;    // 32 KB weight buffer (W2 / W3 / W4h0 / W4h1)
constexpr int L_W1  = 65536;    // [128 n][64 B]
constexpr int L_XS  = 73728;    // x_src [64][16] f32
constexpr int L_B1  = 77824;    // 128 f32
constexpr int L_B2  = L_B1 + 512;
constexpr int L_B3  = L_B2 + 512;
constexpr int L_B4  = L_B3 + 512;   // 256 f32
constexpr int L_DST = L_B4 + 1024;  // 64 i32
constexpr int L_TOT = L_DST + 256;  // 80640 B

__device__ inline unsigned short bfb(float f) {
    __hip_bfloat16 h = __float2bfloat16(f);
    return __builtin_bit_cast(unsigned short, h);
}
__device__ inline unsigned pk2(float a, float b) {
    return (unsigned)bfb(a) | ((unsigned)bfb(b) << 16);
}

// ---- weight reg-staging: 512 threads x 64 B = one 32 KB [128][256B] tile ----
__device__ inline void wload(const char* __restrict__ img, int t, u32x4 w[4]) {
    const int n = t >> 2, q = t & 3;
    const char* src = img + n * 256 + q * 64;
#pragma unroll
    for (int s = 0; s < 4; ++s)
        w[s] = *reinterpret_cast<const u32x4*>(src + 16 * s);
}
__device__ inline void wstore(char* sm, int t, const u32x4 w[4]) {
    const int n = t >> 2, q = t & 3;
#pragma unroll
    for (int s = 0; s < 4; ++s)
        *reinterpret_cast<u32x4*>(sm + L_W + n * 256 + ((q * 64 + s * 16) ^ ((n & 7) << 4))) = w[s];
}

// One padded MFMA layer: out[e][n] = relu(bias[n] + sum_k in[e][k]*W[n][k])
// in/out: [64 e][256B] rows, swizzle byte ^ ((e&7)<<4).
// W: row stride WSTRIDE (256 -> mask 7, 64 -> mask 3).
template<int KSTEPS, int WSTRIDE, bool RELU>
__device__ inline void layer(char* sm, int inOff, int outOff, int wOff, int bOff,
                             int wm, int wn, int lane)
{
    const int r16 = lane & 15, g4 = lane >> 4;
    const int R0 = 16 * wm, C0 = 64 * wn;
    constexpr int WM = (WSTRIDE == 256) ? 7 : 3;
    f32x4 acc[4] = {};
#pragma unroll
    for (int ks = 0; ks < KSTEPS; ++ks) {
        const int kb = ks * 64 + g4 * 16;
        const int r = R0 + r16;
        const bf16x8 a = *reinterpret_cast<const bf16x8*>(sm + inOff + r * 256 + (kb ^ ((r & 7) << 4)));
        bf16x8 b[4];
#pragma unroll
        for (int nf = 0; nf < 4; ++nf) {
            const int n = C0 + 16 * nf + r16;
            b[nf] = *reinterpret_cast<const bf16x8*>(sm + wOff + n * WSTRIDE + (kb ^ ((n & WM) << 4)));
        }
#pragma unroll
        for (int nf = 0; nf < 4; ++nf)
            acc[nf] = __builtin_amdgcn_mfma_f32_16x16x32_bf16(a, b[nf], acc[nf], 0, 0, 0);
    }
    const float* bl = reinterpret_cast<const float*>(sm + bOff);
#pragma unroll
    for (int nf = 0; nf < 4; ++nf) {
        const int n = C0 + 16 * nf + r16;
        const float bb = bl[n];
#pragma unroll
        for (int j = 0; j < 4; ++j) {
            const int r = R0 + g4 * 4 + j;
            float v = acc[nf][j] + bb;
            if (RELU) v = fmaxf(v, 0.f);
            *reinterpret_cast<unsigned short*>(sm + outOff + r * 256 + ((2 * n) ^ ((r & 7) << 4))) = bfb(v);
        }
    }
}

// L4 half h: w[e][n] = acc + b4[128h+n]; msg[e][o] += x[e][i]*w, i=n>>4, o=n&15
__device__ inline void layer4(char* sm, int inOff, int h, int wm, int wn, int lane,
                              float mp[4])
{
    const int r16 = lane & 15, g4 = lane >> 4;
    const int R0 = 16 * wm, C0 = 64 * wn;
    f32x4 acc[4] = {};
#pragma unroll
    for (int ks = 0; ks < 4; ++ks) {
        const int kb = ks * 64 + g4 * 16;
        const int r = R0 + r16;
        const bf16x8 a = *reinterpret_cast<const bf16x8*>(sm + inOff + r * 256 + (kb ^ ((r & 7) << 4)));
        bf16x8 b[4];
#pragma unroll
        for (int nf = 0; nf < 4; ++nf) {
            const int n = C0 + 16 * nf + r16;
            b[nf] = *reinterpret_cast<const bf16x8*>(sm + L_W + n * 256 + (kb ^ ((n & 7) << 4)));
        }
#pragma unroll
        for (int nf = 0; nf < 4; ++nf)
            acc[nf] = __builtin_amdgcn_mfma_f32_16x16x32_bf16(a, b[nf], acc[nf], 0, 0, 0);
    }
    const float* b4l = reinterpret_cast<const float*>(sm + L_B4);
    const float* xs  = reinterpret_cast<const float*>(sm + L_XS);
    float bb[4];
#pragma unroll
    for (int nf = 0; nf < 4; ++nf) bb[nf] = b4l[128 * h + C0 + 16 * nf + r16];
#pragma unroll
    for (int j = 0; j < 4; ++j) {
        const int e = R0 + g4 * 4 + j;
        const float4 xv = *reinterpret_cast<const float4*>(&xs[e * 16 + 8 * h + 4 * wn]);
#pragma unroll
        for (int nf = 0; nf < 4; ++nf)
            mp[j] = fmaf((&xv.x)[nf], acc[nf][j] + bb[nf], mp[j]);
    }
}

__global__ __launch_bounds__(TPB, 4)
void edge_kernel(const float* __restrict__ x, const int* __restrict__ eidx,
                 const float* __restrict__ ea,
                 const float* __restrict__ b1, const float* __restrict__ b2,
                 const float* __restrict__ b3, const float* __restrict__ b4,
                 const char* __restrict__ ws,
                 float* __restrict__ out, float* __restrict__ cnt)
{
    extern __shared__ char sm[];
    const int t    = threadIdx.x;
    const int lane = t & 63;
    const int wave = t >> 6;
    const int wm   = wave >> 1, wn = wave & 1;
    const int e0   = blockIdx.x * EB;
    const int r16  = lane & 15, g4 = lane >> 4;

    // ---- issue W1 + W2 global loads (regs) ----
    u32x4 wreg[4], w1reg[4];
    wload(ws + WS_W2, t, wreg);
    if (t < 128) {
        const char* src = ws + WS_W1 + t * 64;
#pragma unroll
        for (int s = 0; s < 4; ++s)
            w1reg[s] = *reinterpret_cast<const u32x4*>(src + 16 * s);
    }

    // ---- per-edge staging ----
    if (t < 128) {   // edge_attr -> bf16 (k 0..7) in X slot 0
        const int e = t >> 1, hh = t & 1;
        const float4 v = *reinterpret_cast<const float4*>(&ea[(size_t)(e0 + e) * 8 + 4 * hh]);
        uint2 pk; pk.x = pk2(v.x, v.y); pk.y = pk2(v.z, v.w);
        *reinterpret_cast<uint2*>(sm + L_X + e * 256 + ((e & 7) << 4) + hh * 8) = pk;
    }
    if (t < 192) {   // zero k-slots 1..3
        const int e = t & 63, s = 1 + (t >> 6);
        *reinterpret_cast<float4*>(sm + L_X + e * 256 + ((s * 16) ^ ((e & 7) << 4))) =
            make_float4(0.f, 0.f, 0.f, 0.f);
    }
    if (t < 256) {   // gather x[src]
        const int e = t >> 2, q = t & 3;
        const int s = eidx[e0 + e];
        *reinterpret_cast<float4*>(sm + L_XS + e * 64 + 16 * q) =
            *reinterpret_cast<const float4*>(&x[(size_t)s * 16 + 4 * q]);
    }
    if (t < 64) {
        const int d = eidx[E_TOTAL + e0 + t];
        reinterpret_cast<int*>(sm + L_DST)[t] = d;
        unsafeAtomicAdd(&cnt[d], 1.0f);
    }
    if (t < 128) {
        const bool ok = t < 100;
        reinterpret_cast<float*>(sm + L_B1)[t] = ok ? b1[t] : 0.f;
        reinterpret_cast<float*>(sm + L_B2)[t] = ok ? b2[t] : 0.f;
        reinterpret_cast<float*>(sm + L_B3)[t] = ok ? b3[t] : 0.f;
    }
    if (t < 256) reinterpret_cast<float*>(sm + L_B4)[t] = b4[t];

    // ---- write W1/W2 to LDS (compiler inserts the vmcnt waits) ----
    wstore(sm, t, wreg);
    if (t < 128) {
#pragma unroll
        for (int s = 0; s < 4; ++s)
            *reinterpret_cast<u32x4*>(sm + L_W1 + t * 64 + ((s * 16) ^ ((t & 3) << 4))) = w1reg[s];
    }
    __syncthreads();

    wload(ws + WS_W3, t, wreg);                                   // W3 in flight over L1+L2
    layer<1, 64,  true>(sm, L_X, L_Y, L_W1, L_B1, wm, wn, lane);  // L1
    __syncthreads();
    layer<4, 256, true>(sm, L_Y, L_X, L_W,  L_B2, wm, wn, lane);  // L2
    __syncthreads();
    wstore(sm, t, wreg);
    __syncthreads();

    wload(ws + WS_W4, t, wreg);                                   // W4h0 over L3
    layer<4, 256, true>(sm, L_X, L_Y, L_W,  L_B3, wm, wn, lane);  // L3
    __syncthreads();
    wstore(sm, t, wreg);
    __syncthreads();

    wload(ws + WS_W4 + 32768, t, wreg);                           // W4h1 over L4h0
    float mp[4] = {};
    layer4(sm, L_Y, 0, wm, wn, lane, mp);
    __syncthreads();
    wstore(sm, t, wreg);
    __syncthreads();
    layer4(sm, L_Y, 1, wm, wn, lane, mp);

    // ---- combine n-wave partials and scatter ----
    float* msgb = reinterpret_cast<float*>(sm + L_X);   // X is dead after L3
    if (wn == 0) {
#pragma unroll
        for (int j = 0; j < 4; ++j)
            msgb[(16 * wm + g4 * 4 + j) * 16 + r16] = mp[j];
    }
    __syncthreads();
    if (wn == 1) {
        const int* dsti = reinterpret_cast<const int*>(sm + L_DST);
#pragma unroll
        for (int j = 0; j < 4; ++j) {
            const int e = 16 * wm + g4 * 4 + j;
            const float v = mp[j] + msgb[e * 16 + r16];
            unsafeAtomicAdd(&out[(size_t)dsti[e] * 16 + r16], v);
        }
    }
}

// linear bf16 weight images + zero cnt
__global__ __launch_bounds__(256)
void prep_kernel(const float* __restrict__ W1, const float* __restrict__ W2,
                 const float* __restrict__ W3, const float* __restrict__ W4,
                 char* __restrict__ ws)
{
    const int id = blockIdx.x * 256 + threadIdx.x;
    if (id < N_NODES) reinterpret_cast<float*>(ws + WS_CNT)[id] = 0.f;
    if (id >= 69632) return;
    float v = 0.f;
    if (id < 4096) {
        const int n = id >> 5, k = id & 31;
        if (n < 100 && k < 8) v = W1[k * 100 + n];
    } else if (id < 20480) {
        const int j = id - 4096, n = j >> 7, k = j & 127;
        if (n < 100 && k < 100) v = W2[k * 100 + n];
    } else if (id < 36864) {
        const int j = id - 20480, n = j >> 7, k = j & 127;
        if (n < 100 && k < 100) v = W3[k * 100 + n];
    } else {
        const int j = id - 36864, n = j >> 7, k = j & 127;
        if (k < 100) v = W4[k * 256 + n];
    }
    reinterpret_cast<unsigned short*>(ws + WS_W1)[id] = bfb(v);
}

// out[n][o] = x[n]@root[:,o] + out[n][o]/max(cnt[n],1) + bias[o]   (in place)
__global__ __launch_bounds__(256)
void node_kernel(const float* __restrict__ x, const float* __restrict__ root,
                 const float* __restrict__ bias, const float* __restrict__ cnt,
                 float* __restrict__ out)
{
    const int n = blockIdx.x * blockDim.x + threadIdx.x;
    if (n >= N_NODES) return;
    float xr[16];
#pragma unroll
    for (int q = 0; q < 4; ++q) {
        const float4 v = *reinterpret_cast<const float4*>(&x[(size_t)n * 16 + 4 * q]);
        xr[4 * q] = v.x; xr[4 * q + 1] = v.y; xr[4 * q + 2] = v.z; xr[4 * q + 3] = v.w;
    }
    const float inv = 1.f / fmaxf(cnt[n], 1.f);
#pragma unroll
    for (int q = 0; q < 4; ++q) {
        float4 o4 = *reinterpret_cast<float4*>(&out[(size_t)n * 16 + 4 * q]);
        float res[4];
#pragma unroll
        for (int j = 0; j < 4; ++j) {
            const int o = 4 * q + j;
            float dot = 0.f;
#pragma unroll
            for (int i = 0; i < 16; ++i)
                dot = fmaf(xr[i], root[i * 16 + o], dot);
            res[j] = dot + (&o4.x)[j] * inv + bias[o];
        }
        *reinterpret_cast<float4*>(&out[(size_t)n * 16 + 4 * q]) = make_float4(res[0], res[1], res[2], res[3]);
    }
}

extern "C" void kernel_launch(void* const* d_in, const int* in_sizes, int n_in,
                              void* d_out, int out_size, void* d_ws, size_t ws_size,
                              hipStream_t stream)
{
    const float* x    = (const float*)d_in[0];
    const int*   eidx = (const int*)  d_in[1];
    const float* ea   = (const float*)d_in[2];
    const float* W1   = (const float*)d_in[3];
    const float* b1   = (const float*)d_in[4];
    const float* W2   = (const float*)d_in[5];
    const float* b2   = (const float*)d_in[6];
    const float* W3   = (const float*)d_in[7];
    const float* b3   = (const float*)d_in[8];
    const float* W4   = (const float*)d_in[9];
    const float* b4   = (const float*)d_in[10];
    const float* root = (const float*)d_in[11];
    const float* bias = (const float*)d_in[12];
    float* out = (float*)d_out;
    char*  ws  = (char*)d_ws;
    float* cnt = (float*)d_ws;

    (void)in_sizes; (void)n_in; (void)ws_size;

    hipFuncSetAttribute((const void*)edge_kernel,
                        hipFuncAttributeMaxDynamicSharedMemorySize, L_TOT);

    hipMemsetAsync(d_out, 0, (size_t)out_size * sizeof(float), stream);

    hipLaunchKernelGGL(prep_kernel, dim3(272), dim3(256), 0, stream, W1, W2, W3, W4, ws);
    hipLaunchKernelGGL(edge_kernel, dim3(E_TOTAL / EB), dim3(TPB), L_TOT, stream,
                       x, eidx, ea, b1, b2, b3, b4, ws, out, cnt);
    hipLaunchKernelGGL(node_kernel, dim3((N_NODES + 255) / 256), dim3(256), 0, stream,
                       x, root, bias, cnt, out);
}

// Round 4
// 339.186 us; speedup vs baseline: 6.8948x; 1.0028x over previous
//
#include <hip/hip_runtime.h>
#include <hip/hip_bf16.h>

// ---------------- problem constants ----------------
constexpr int N_NODES = 50000;
constexpr int E_TOTAL = 800000;
constexpr int EB   = 64;              // edges per tile
constexpr int NT   = E_TOTAL / EB;    // 12500 tiles
constexpr int GRID = 256;             // persistent blocks, 1 per CU
constexpr int TPB  = 512;             // 8 waves: 2 m x 4 n

typedef __attribute__((ext_vector_type(8))) short bf16x8;
typedef __attribute__((ext_vector_type(4))) float f32x4;

// ---------------- workspace byte offsets ----------------
constexpr size_t WS_CNT = 0;                  // N_NODES f32
constexpr size_t WS_W1  = 200704;             // [128 n][32 k] bf16 linear
constexpr size_t WS_W2  = WS_W1 + 8192;       // [128 n][128 k] linear
constexpr size_t WS_W3  = WS_W2 + 32768;      // [128 n][128 k] linear
constexpr size_t WS_W4  = WS_W3 + 32768;      // [256 n][128 k] SWIZZLED rows

// ---------------- LDS byte offsets ----------------
constexpr int L_W4  = 0;         // 65536 B, persistent (swizzled image)
constexpr int L_HA  = 65536;     // [64][256B] bf16, swizzled
constexpr int L_HB  = 81920;     // [64][256B]
constexpr int L_EA  = 98304;     // [64][64B] bf16 linear (k-pad 32)
constexpr int L_XS  = 102400;    // [64][16] f32
constexpr int L_MSG = 106496;    // 4 slabs x [64][20] f32 = 20480 B
constexpr int L_DST = 126976;    // 2 x 64 i32
constexpr int L_TOT = 127488;

__device__ inline unsigned short bfb(float f) {
    __hip_bfloat16 h = __float2bfloat16(f);
    return __builtin_bit_cast(unsigned short, h);
}
__device__ inline unsigned pk2(float a, float b) {
    return (unsigned)bfb(a) | ((unsigned)bfb(b) << 16);
}

// async 16B/lane global->LDS copy; bytes multiple of 1024, linear both sides
__device__ inline void stage(const char* g, char* l, int bytes, int t) {
    const int wave = t >> 6, lane = t & 63;
    for (int c = wave; c * 1024 < bytes; c += 8) {
        __builtin_amdgcn_global_load_lds(
            (const __attribute__((address_space(1))) void*)(g + c * 1024 + lane * 16),
            (__attribute__((address_space(3))) void*)(l + c * 1024), 16, 0, 0);
    }
}

// hidden layer, B-operand from registers.
// in: SWZ? [64][256B] swizzled : [64][64B] linear. out: [64][256B] swizzled.
template<int KSTEPS, bool SWZ>
__device__ inline void layerR(char* sm, int inOff, int outOff,
                              const bf16x8 (&wf)[2][KSTEPS], const float (&bb)[2],
                              int wm, int wn, int lane)
{
    const int r16 = lane & 15, g4 = lane >> 4;
    f32x4 acc[2][2] = {};
#pragma unroll
    for (int ks = 0; ks < KSTEPS; ++ks) {
        const int kb = ks * 64 + g4 * 16;
        bf16x8 a[2];
#pragma unroll
        for (int mb = 0; mb < 2; ++mb) {
            const int r = 32 * wm + 16 * mb + r16;
            a[mb] = SWZ
                ? *reinterpret_cast<const bf16x8*>(sm + inOff + r * 256 + (kb ^ ((r & 7) << 4)))
                : *reinterpret_cast<const bf16x8*>(sm + inOff + r * 64 + kb);
        }
#pragma unroll
        for (int nf = 0; nf < 2; ++nf)
#pragma unroll
            for (int mb = 0; mb < 2; ++mb)
                acc[mb][nf] = __builtin_amdgcn_mfma_f32_16x16x32_bf16(a[mb], wf[nf][ks], acc[mb][nf], 0, 0, 0);
    }
#pragma unroll
    for (int nf = 0; nf < 2; ++nf) {
        const int n = 32 * wn + 16 * nf + r16;
#pragma unroll
        for (int mb = 0; mb < 2; ++mb)
#pragma unroll
            for (int j = 0; j < 4; ++j) {
                const int r = 32 * wm + 16 * mb + g4 * 4 + j;
                const float v = fmaxf(acc[mb][nf][j] + bb[nf], 0.f);
                *reinterpret_cast<unsigned short*>(sm + outOff + r * 256 + ((2 * n) ^ ((r & 7) << 4))) = bfb(v);
            }
    }
}

__global__ __launch_bounds__(TPB, 2)
void edge_kernel(const float* __restrict__ x, const int* __restrict__ eidx,
                 const float* __restrict__ ea,
                 const float* __restrict__ b1, const float* __restrict__ b2,
                 const float* __restrict__ b3, const float* __restrict__ b4,
                 const char* __restrict__ ws,
                 float* __restrict__ out, float* __restrict__ cnt)
{
    extern __shared__ char sm[];
    const int t    = threadIdx.x;
    const int lane = t & 63;
    const int wave = t >> 6;
    const int wm   = wave >> 2, wn = wave & 3;     // 2 m-waves x 4 n-waves
    const int r16  = lane & 15, g4 = lane >> 4;

    // ---- persistent weight fragments (registers) + biases ----
    bf16x8 wf1[2][1], wf2[2][4], wf3[2][4];
    float bb1[2], bb2[2], bb3[2], bb4[4];
#pragma unroll
    for (int nf = 0; nf < 2; ++nf) {
        const int n = 32 * wn + 16 * nf + r16;
        wf1[nf][0] = *reinterpret_cast<const bf16x8*>(ws + WS_W1 + n * 64 + g4 * 16);
#pragma unroll
        for (int ks = 0; ks < 4; ++ks) {
            wf2[nf][ks] = *reinterpret_cast<const bf16x8*>(ws + WS_W2 + n * 256 + ks * 64 + g4 * 16);
            wf3[nf][ks] = *reinterpret_cast<const bf16x8*>(ws + WS_W3 + n * 256 + ks * 64 + g4 * 16);
        }
        bb1[nf] = (n < 100) ? b1[n] : 0.f;
        bb2[nf] = (n < 100) ? b2[n] : 0.f;
        bb3[nf] = (n < 100) ? b3[n] : 0.f;
    }
#pragma unroll
    for (int nf = 0; nf < 4; ++nf) bb4[nf] = b4[64 * wn + 16 * nf + r16];

    // ---- W4 into LDS once (image pre-swizzled -> linear copy) ----
    stage(ws + WS_W4, sm + L_W4, 65536, t);

    // zero EA pad bytes 16..64 of each row (written once, never dirtied)
    if (t < 192) {
        const int e = t & 63, s = 1 + (t >> 6);
        *reinterpret_cast<float4*>(sm + L_EA + e * 64 + s * 16) = make_float4(0.f, 0.f, 0.f, 0.f);
    }

    // ---- stage first tile into registers ----
    float4 eaR, xvR; int dstR = 0;
    {
        const int e0 = blockIdx.x * EB;
        if (t < 128) eaR = *reinterpret_cast<const float4*>(&ea[(size_t)(e0 + (t >> 1)) * 8 + (t & 1) * 4]);
        if (t < 256) {
            const int s = eidx[e0 + (t >> 2)];
            xvR = *reinterpret_cast<const float4*>(&x[(size_t)s * 16 + (t & 3) * 4]);
        }
        if (t < 64) dstR = eidx[E_TOTAL + e0 + t];
    }
    __syncthreads();   // drains W4 global_load_lds + EA pad zeros

    int parity = 0;
    for (int tile = blockIdx.x; tile < NT; tile += GRID) {
        // ---- P0: write staged regs -> LDS; issue next tile's loads ----
        if (t < 128) {
            const int e = t >> 1, hh = t & 1;
            uint2 pk; pk.x = pk2(eaR.x, eaR.y); pk.y = pk2(eaR.z, eaR.w);
            *reinterpret_cast<uint2*>(sm + L_EA + e * 64 + hh * 8) = pk;
        }
        if (t < 256) *reinterpret_cast<float4*>(sm + L_XS + (t >> 2) * 64 + (t & 3) * 16) = xvR;
        if (t < 64)  reinterpret_cast<int*>(sm + L_DST)[parity * 64 + t] = dstR;

        const int nxt = tile + GRID;
        if (nxt < NT) {
            const int e0 = nxt * EB;
            if (t < 128) eaR = *reinterpret_cast<const float4*>(&ea[(size_t)(e0 + (t >> 1)) * 8 + (t & 1) * 4]);
            if (t < 256) {
                const int s = eidx[e0 + (t >> 2)];
                xvR = *reinterpret_cast<const float4*>(&x[(size_t)s * 16 + (t & 3) * 4]);
            }
            if (t < 64) dstR = eidx[E_TOTAL + e0 + t];
        }
        __syncthreads();                                            // A

        layerR<1, false>(sm, L_EA, L_HA, wf1, bb1, wm, wn, lane);   // L1
        __syncthreads();                                            // B
        layerR<4, true >(sm, L_HA, L_HB, wf2, bb2, wm, wn, lane);   // L2
        __syncthreads();                                            // C
        layerR<4, true >(sm, L_HB, L_HA, wf3, bb3, wm, wn, lane);   // L3
        __syncthreads();                                            // D

        // ---- L4 (W4 from LDS) + fold x[src] -> per-wave msg partials ----
        float mp[2][4] = {};
        {
            f32x4 acc[2][4] = {};
#pragma unroll
            for (int ks = 0; ks < 4; ++ks) {
                const int kb = ks * 64 + g4 * 16;
                bf16x8 a[2];
#pragma unroll
                for (int mb = 0; mb < 2; ++mb) {
                    const int r = 32 * wm + 16 * mb + r16;
                    a[mb] = *reinterpret_cast<const bf16x8*>(sm + L_HA + r * 256 + (kb ^ ((r & 7) << 4)));
                }
#pragma unroll
                for (int nf = 0; nf < 4; ++nf) {
                    const int n = 64 * wn + 16 * nf + r16;
                    const bf16x8 b = *reinterpret_cast<const bf16x8*>(sm + L_W4 + n * 256 + (kb ^ ((n & 7) << 4)));
#pragma unroll
                    for (int mb = 0; mb < 2; ++mb)
                        acc[mb][nf] = __builtin_amdgcn_mfma_f32_16x16x32_bf16(a[mb], b, acc[mb][nf], 0, 0, 0);
                }
            }
            const float* xs = reinterpret_cast<const float*>(sm + L_XS);
#pragma unroll
            for (int mb = 0; mb < 2; ++mb)
#pragma unroll
                for (int j = 0; j < 4; ++j) {
                    const int e = 32 * wm + 16 * mb + g4 * 4 + j;
                    const float4 xv = *reinterpret_cast<const float4*>(&xs[e * 16 + 4 * wn]);
#pragma unroll
                    for (int nf = 0; nf < 4; ++nf)
                        mp[mb][j] = fmaf((&xv.x)[nf], acc[mb][nf][j] + bb4[nf], mp[mb][j]);
                }
        }
        {   // write per-n-wave partial slab (stride 20 f32 rows)
            float* msg = reinterpret_cast<float*>(sm + L_MSG) + wn * 1280;
#pragma unroll
            for (int mb = 0; mb < 2; ++mb)
#pragma unroll
                for (int j = 0; j < 4; ++j) {
                    const int e = 32 * wm + 16 * mb + g4 * 4 + j;
                    msg[e * 20 + r16] = mp[mb][j];
                }
        }
        __syncthreads();                                            // E

        // ---- reduce 4 slabs + scatter ----
        if (t < 256) {
            const int e = t >> 2, o0 = (t & 3) * 4;
            const float* m = reinterpret_cast<const float*>(sm + L_MSG);
            const float4 s0 = *reinterpret_cast<const float4*>(m + 0 * 1280 + e * 20 + o0);
            const float4 s1 = *reinterpret_cast<const float4*>(m + 1 * 1280 + e * 20 + o0);
            const float4 s2 = *reinterpret_cast<const float4*>(m + 2 * 1280 + e * 20 + o0);
            const float4 s3 = *reinterpret_cast<const float4*>(m + 3 * 1280 + e * 20 + o0);
            const int d = reinterpret_cast<const int*>(sm + L_DST)[parity * 64 + e];
            unsafeAtomicAdd(&out[(size_t)d * 16 + o0 + 0], s0.x + s1.x + s2.x + s3.x);
            unsafeAtomicAdd(&out[(size_t)d * 16 + o0 + 1], s0.y + s1.y + s2.y + s3.y);
            unsafeAtomicAdd(&out[(size_t)d * 16 + o0 + 2], s0.z + s1.z + s2.z + s3.z);
            unsafeAtomicAdd(&out[(size_t)d * 16 + o0 + 3], s0.w + s1.w + s2.w + s3.w);
            if ((t & 3) == 0) unsafeAtomicAdd(&cnt[d], 1.0f);
        }
        parity ^= 1;
    }
}

// bf16 weight images (W1/2/3 linear n-major, W4 swizzled rows) + zero cnt
__global__ __launch_bounds__(256)
void prep_kernel(const float* __restrict__ W1, const float* __restrict__ W2,
                 const float* __restrict__ W3, const float* __restrict__ W4,
                 char* __restrict__ ws)
{
    const int id = blockIdx.x * 256 + threadIdx.x;
    if (id < N_NODES) reinterpret_cast<float*>(ws + WS_CNT)[id] = 0.f;
    if (id >= 69632) return;
    float v = 0.f;
    if (id < 4096) {
        const int n = id >> 5, k = id & 31;
        if (n < 100 && k < 8) v = W1[k * 100 + n];
        reinterpret_cast<unsigned short*>(ws + WS_W1)[id] = bfb(v);
    } else if (id < 20480) {
        const int j = id - 4096, n = j >> 7, k = j & 127;
        if (n < 100 && k < 100) v = W2[k * 100 + n];
        reinterpret_cast<unsigned short*>(ws + WS_W2)[j] = bfb(v);
    } else if (id < 36864) {
        const int j = id - 20480, n = j >> 7, k = j & 127;
        if (n < 100 && k < 100) v = W3[k * 100 + n];
        reinterpret_cast<unsigned short*>(ws + WS_W3)[j] = bfb(v);
    } else {
        const int j = id - 36864, n = j >> 7, k = j & 127;
        if (k < 100) v = W4[k * 256 + n];
        *reinterpret_cast<unsigned short*>(ws + WS_W4 + n * 256 + ((2 * k) ^ ((n & 7) << 4))) = bfb(v);
    }
}

// out[n][o] = x[n]@root[:,o] + out[n][o]/max(cnt[n],1) + bias[o]   (in place)
__global__ __launch_bounds__(256)
void node_kernel(const float* __restrict__ x, const float* __restrict__ root,
                 const float* __restrict__ bias, const float* __restrict__ cnt,
                 float* __restrict__ out)
{
    const int n = blockIdx.x * blockDim.x + threadIdx.x;
    if (n >= N_NODES) return;
    float xr[16];
#pragma unroll
    for (int q = 0; q < 4; ++q) {
        const float4 v = *reinterpret_cast<const float4*>(&x[(size_t)n * 16 + 4 * q]);
        xr[4 * q] = v.x; xr[4 * q + 1] = v.y; xr[4 * q + 2] = v.z; xr[4 * q + 3] = v.w;
    }
    const float inv = 1.f / fmaxf(cnt[n], 1.f);
#pragma unroll
    for (int q = 0; q < 4; ++q) {
        float4 o4 = *reinterpret_cast<float4*>(&out[(size_t)n * 16 + 4 * q]);
        float res[4];
#pragma unroll
        for (int j = 0; j < 4; ++j) {
            const int o = 4 * q + j;
            float dot = 0.f;
#pragma unroll
            for (int i = 0; i < 16; ++i)
                dot = fmaf(xr[i], root[i * 16 + o], dot);
            res[j] = dot + (&o4.x)[j] * inv + bias[o];
        }
        *reinterpret_cast<float4*>(&out[(size_t)n * 16 + 4 * q]) = make_float4(res[0], res[1], res[2], res[3]);
    }
}

extern "C" void kernel_launch(void* const* d_in, const int* in_sizes, int n_in,
                              void* d_out, int out_size, void* d_ws, size_t ws_size,
                              hipStream_t stream)
{
    const float* x    = (const float*)d_in[0];
    const int*   eidx = (const int*)  d_in[1];
    const float* ea   = (const float*)d_in[2];
    const float* W1   = (const float*)d_in[3];
    const float* b1   = (const float*)d_in[4];
    const float* W2   = (const float*)d_in[5];
    const float* b2   = (const float*)d_in[6];
    const float* W3   = (const float*)d_in[7];
    const float* b3   = (const float*)d_in[8];
    const float* W4   = (const float*)d_in[9];
    const float* b4   = (const float*)d_in[10];
    const float* root = (const float*)d_in[11];
    const float* bias = (const float*)d_in[12];
    float* out = (float*)d_out;
    char*  ws  = (char*)d_ws;
    float* cnt = (float*)d_ws;

    (void)in_sizes; (void)n_in; (void)ws_size;

    hipFuncSetAttribute((const void*)edge_kernel,
                        hipFuncAttributeMaxDynamicSharedMemorySize, L_TOT);

    hipMemsetAsync(d_out, 0, (size_t)out_size * sizeof(float), stream);

    hipLaunchKernelGGL(prep_kernel, dim3(272), dim3(256), 0, stream, W1, W2, W3, W4, ws);
    hipLaunchKernelGGL(edge_kernel, dim3(GRID), dim3(TPB), L_TOT, stream,
                       x, eidx, ea, b1, b2, b3, b4, ws, out, cnt);
    hipLaunchKernelGGL(node_kernel, dim3((N_NODES + 255) / 256), dim3(256), 0, stream,
                       x, root, bias, cnt, out);
}